// Round 10
// baseline (90.502 us; speedup 1.0000x reference)
//
#include <hip/hip_runtime.h>
#include <hip/hip_bf16.h>

typedef __attribute__((ext_vector_type(8))) short short8;
typedef __attribute__((ext_vector_type(4))) float floatx4;

#define D_DIM 128
#define SCALE_F 1.6986436f          /* sqrt(2*log2(e)); (s*a)·(s*b) = 2*log2(e)*a·b */
#define CS 16                        /* col-tile splitters (grid.y) */
#define CTILE 64                     /* columns per LDS tile */
#define MREP 2                       /* 16-row MFMA blocks per wave */
#define NRXB 64                      /* 128-row blocks over 8192 rows */

typedef __attribute__((address_space(1))) const unsigned int GUI;
typedef __attribute__((address_space(3))) unsigned int LUI;
#define GLOAD16(g, l) __builtin_amdgcn_global_load_lds((GUI*)(g), (LUI*)(l), 16, 0, 0)

// ---- prep: normalize rows, scale by sqrt(2log2e) -> bf16 Z; fp32 pos dots ----
__global__ void prep_kernel(const float* __restrict__ zi,
                            const float* __restrict__ zj,
                            __hip_bfloat16* __restrict__ Zb,
                            float* __restrict__ posdot, int N) {
    int r = blockIdx.x * 4 + (threadIdx.x >> 6);   // 4 rows per 256-thread block
    int t = threadIdx.x & 63;
    const float* pi = zi + (size_t)r * D_DIM;
    const float* pj = zj + (size_t)r * D_DIM;
    float a0 = pi[t], a1 = pi[t + 64];
    float b0 = pj[t], b1 = pj[t + 64];
    float ssi = a0*a0 + a1*a1;
    float ssj = b0*b0 + b1*b1;
    float sij = a0*b0 + a1*b1;
#pragma unroll
    for (int off = 1; off < 64; off <<= 1) {
        ssi += __shfl_xor(ssi, off);
        ssj += __shfl_xor(ssj, off);
        sij += __shfl_xor(sij, off);
    }
    float ni = sqrtf(ssi), nj = sqrtf(ssj);
    float ri = SCALE_F / ni, rj = SCALE_F / nj;
    __hip_bfloat16* zr0 = Zb + (size_t)r * D_DIM;
    __hip_bfloat16* zr1 = Zb + (size_t)(r + N) * D_DIM;
    zr0[t]      = __float2bfloat16(a0 * ri);
    zr0[t + 64] = __float2bfloat16(a1 * ri);
    zr1[t]      = __float2bfloat16(b0 * rj);
    zr1[t + 64] = __float2bfloat16(b1 * rj);
    if (t == 0) posdot[r] = sij / fmaxf(ni * nj, 1e-8f);
}

// ---- main: symmetric fused Gram x exp2, row-sums + col-sums ----
// grid (32 pairs, CS); 512 threads = 8 waves: 4 M-waves (32 rows) x 2 N-halves.
// Block (p,q): row-blocks rx=p and rx'=63-p (128 rows each); upper-triangle
// col-tiles k0, k0+16, ... of each. Each exp'd element feeds the row-sum AND
// (via kg-shuffle reduce) the col-sum plane colpart[rx*4+mw][col].
__global__ __launch_bounds__(512, 4)
void main_kernel(const ushort* __restrict__ Zu,
                 float* __restrict__ rowpart,
                 float* __restrict__ colpart, int N2) {
    __shared__ ushort Btile[2][CTILE * D_DIM];   // 2 x 16 KB

    const int tid  = threadIdx.x;
    const int lane = tid & 63;
    const int wave = tid >> 6;      // 0..7
    const int mw   = wave & 3;      // M-wave: which 32-row group
    const int nh   = wave >> 2;     // N-half: which 32 cols of the tile
    const int m    = lane & 15;
    const int kg   = lane >> 4;
    const int q    = blockIdx.y;
    const int pair = blockIdx.x;
    const int rxA  = pair;          // 0..31
    const int rxB  = 63 - pair;     // 63..32
    const int K1   = 128 - 2 * rxA;

    // staging coords (shared by both phases): LDS dest LINEAR, source pre-swizzled
    const int srow0 = tid >> 4,        sslot0 = (tid & 15) ^ (srow0 & 7);
    const int srow1 = 32 + (tid >> 4), sslot1 = (tid & 15) ^ (srow1 & 7);
    const size_t tadv = (size_t)CS * CTILE * D_DIM;   // cols advance 1024/tile-step

    for (int ph = 0; ph < 2; ++ph) {
        const int rx0 = ph ? rxB : rxA;
        const int K   = ph ? (128 - 2 * rxB) : K1;
        const int k0  = ph ? ((q - K1) & 15) : q;
        const int nt  = (K > k0) ? ((K - k0 + 15) >> 4) : 0;
        const int rwave0 = rx0 * 128 + mw * 32;

        // A fragments: 2 row-blocks x 4 k-steps = 32 VGPRs, pinned resident.
        short8 afrag[MREP][4];
#pragma unroll
        for (int rb = 0; rb < MREP; ++rb) {
            const ushort* ap = Zu + (size_t)(rwave0 + rb * 16 + m) * D_DIM + kg * 8;
#pragma unroll
            for (int ks = 0; ks < 4; ++ks)
                afrag[rb][ks] = *(const short8*)(ap + ks * 32);
        }
#pragma unroll
        for (int rb = 0; rb < MREP; ++rb)
#pragma unroll
            for (int ks = 0; ks < 4; ++ks)
                asm volatile("" : "+v"(afrag[rb][ks]));

        float rowacc[MREP][4];
#pragma unroll
        for (int rb = 0; rb < MREP; ++rb)
#pragma unroll
            for (int g = 0; g < 4; ++g) rowacc[rb][g] = 0.0f;

        if (nt > 0) {
            const int c0base = rx0 * 128 + k0 * 64;
            const ushort* gsrc0 = Zu + (size_t)(c0base + srow0) * D_DIM + sslot0 * 8;
            const ushort* gsrc1 = Zu + (size_t)(c0base + srow1) * D_DIM + sslot1 * 8;

            GLOAD16(gsrc0, &Btile[0][(size_t)tid * 8]);
            GLOAD16(gsrc1, &Btile[0][(size_t)(512 + tid) * 8]);
            __syncthreads();

            for (int t = 0; t < nt; ++t) {
                if (t + 1 < nt) {
                    ushort* nbuf = Btile[(t + 1) & 1];
                    GLOAD16(gsrc0 + (size_t)(t + 1) * tadv, &nbuf[(size_t)tid * 8]);
                    GLOAD16(gsrc1 + (size_t)(t + 1) * tadv, &nbuf[(size_t)(512 + tid) * 8]);
                }

                const ushort* buf = Btile[t & 1];
                const int c0 = c0base + t * (CS * CTILE);
                const bool dt = (t == 0) && (k0 < 2);   // diagonal 128-square tile

#pragma unroll
                for (int s2 = 0; s2 < 2; ++s2) {
                    const int brow = nh * 32 + s2 * 16 + m;
                    short8 bfrag[4];
#pragma unroll
                    for (int ks = 0; ks < 4; ++ks) {
                        int ss = (ks * 4 + kg) ^ (brow & 7);
                        bfrag[ks] = *(const short8*)&buf[brow * D_DIM + ss * 8];
                    }
                    const int gc = c0 + brow;   // this lane's global column
                    float cf = 0.0f;
#pragma unroll
                    for (int rb = 0; rb < MREP; ++rb) {
                        floatx4 ac0 = {0.f, 0.f, 0.f, 0.f};
                        floatx4 ac1 = {0.f, 0.f, 0.f, 0.f};
                        ac0 = __builtin_amdgcn_mfma_f32_16x16x32_bf16(afrag[rb][0], bfrag[0], ac0, 0, 0, 0);
                        ac1 = __builtin_amdgcn_mfma_f32_16x16x32_bf16(afrag[rb][2], bfrag[2], ac1, 0, 0, 0);
                        ac0 = __builtin_amdgcn_mfma_f32_16x16x32_bf16(afrag[rb][1], bfrag[1], ac0, 0, 0, 0);
                        ac1 = __builtin_amdgcn_mfma_f32_16x16x32_bf16(afrag[rb][3], bfrag[3], ac1, 0, 0, 0);
#pragma unroll
                        for (int g = 0; g < 4; ++g) {
                            float arg = ac0[g] + ac1[g];
                            if (dt) {
                                int gr = rwave0 + rb * 16 + kg * 4 + g;
                                arg = (gc > gr) ? arg : -1000.0f;   // strict upper triangle
                            }
                            float e = __builtin_amdgcn_exp2f(arg);
                            rowacc[rb][g] += e;
                            cf += e;
                        }
                    }
                    // col-sum over this wave's 32 rows: reduce across kg groups
                    cf += __shfl_xor(cf, 16);
                    cf += __shfl_xor(cf, 32);
                    if (lane < 16)
                        colpart[(size_t)(rx0 * 4 + mw) * N2 + gc] = cf;
                }
                __syncthreads();
            }
        }

        // row partials: reduce across the 16 column lanes, write plane (q*2+nh)
#pragma unroll
        for (int rb = 0; rb < MREP; ++rb)
#pragma unroll
            for (int g = 0; g < 4; ++g) {
                float v = rowacc[rb][g];
                v += __shfl_xor(v, 1);
                v += __shfl_xor(v, 2);
                v += __shfl_xor(v, 4);
                v += __shfl_xor(v, 8);
                if (m == 0) {
                    int grow = rwave0 + rb * 16 + kg * 4 + g;
                    rowpart[(size_t)(q * 2 + nh) * N2 + grow] = v;
                }
            }
        if (ph == 0) __syncthreads();   // Btile safe before phase-2 prologue
    }
}

// ---- finalize stage 1: per-row loss, 32-block partial sums ----
__global__ void finalize1_kernel(const float* __restrict__ rowpart,
                                 const float* __restrict__ colpart,
                                 const float* __restrict__ posdot,
                                 float* __restrict__ bpart, int N2, int NP) {
    __shared__ float red[4];
    int tid = threadIdx.x;                       // 0..255
    int r = blockIdx.x * 256 + tid;              // one row per thread
    float denom = 0.0f;
#pragma unroll
    for (int p = 0; p < 2 * CS; ++p) denom += rowpart[(size_t)p * N2 + r];
    // transposed (c < r) contributions: col-planes of row-blocks rx <= r/128
    int nplanes = ((r >> 7) + 1) * 4;
    for (int pl = 0; pl < nplanes; ++pl)
        denom += colpart[(size_t)pl * N2 + r];
    float pos = posdot[r < NP ? r : r - NP];
    float v = logf(denom) - 2.0f * pos;          // -log(num/denom), 1/t = 2
#pragma unroll
    for (int off = 1; off < 64; off <<= 1) v += __shfl_xor(v, off);
    if ((tid & 63) == 0) red[tid >> 6] = v;
    __syncthreads();
    if (tid == 0) bpart[blockIdx.x] = red[0] + red[1] + red[2] + red[3];
}

// ---- finalize stage 2: mean ----
__global__ void finalize2_kernel(const float* __restrict__ bpart,
                                 float* __restrict__ out, int nb, int N2) {
    int t = threadIdx.x;  // 64
    float v = (t < nb) ? bpart[t] : 0.0f;
#pragma unroll
    for (int off = 1; off < 64; off <<= 1) v += __shfl_xor(v, off);
    if (t == 0) out[0] = v / (float)N2;
}

extern "C" void kernel_launch(void* const* d_in, const int* in_sizes, int n_in,
                              void* d_out, int out_size, void* d_ws, size_t ws_size,
                              hipStream_t stream) {
    const float* zi = (const float*)d_in[0];
    const float* zj = (const float*)d_in[1];
    const int N  = in_sizes[0] / D_DIM;   // 4096
    const int N2 = 2 * N;                 // 8192

    char* w = (char*)d_ws;
    __hip_bfloat16* Zb = (__hip_bfloat16*)w;
    size_t off = (size_t)N2 * D_DIM * sizeof(__hip_bfloat16);        // 2 MB
    float* posdot  = (float*)(w + off);  off += (size_t)N  * sizeof(float);
    float* rowpart = (float*)(w + off);  off += (size_t)(2 * CS) * N2 * sizeof(float);   // 1 MB
    float* colpart = (float*)(w + off);  off += (size_t)(NRXB * 4) * N2 * sizeof(float); // 8 MB
    float* bpart   = (float*)(w + off);

    prep_kernel<<<N / 4, 256, 0, stream>>>(zi, zj, Zb, posdot, N);
    dim3 grid(32, CS);
    main_kernel<<<grid, 512, 0, stream>>>((const ushort*)Zb, rowpart, colpart, N2);
    const int nb = N2 / 256;  // 32
    finalize1_kernel<<<nb, 256, 0, stream>>>(rowpart, colpart, posdot, bpart, N2, N);
    finalize2_kernel<<<1, 64, 0, stream>>>(bpart, (float*)d_out, nb, N2);
}

// Round 11
// 42.350 us; speedup vs baseline: 2.1370x; 2.1370x over previous
//
#include <hip/hip_runtime.h>
#include <hip/hip_bf16.h>

typedef __attribute__((ext_vector_type(8))) short short8;
typedef __attribute__((ext_vector_type(4))) float floatx4;

#define D_DIM 128
#define SCALE_F 1.6986436f          /* sqrt(2*log2(e)); (s*a)·(s*b) = 2*log2(e)*a·b */
#define CS 16                        /* col-tile splitters (grid.y) */
#define CTILE 64                     /* columns per LDS tile */
#define MREP 2                       /* 16-row MFMA blocks per wave */
#define NRXB 64                      /* 128-row blocks over 8192 rows */

typedef __attribute__((address_space(1))) const unsigned int GUI;
typedef __attribute__((address_space(3))) unsigned int LUI;
#define GLOAD16(g, l) __builtin_amdgcn_global_load_lds((GUI*)(g), (LUI*)(l), 16, 0, 0)

// ---- prep: normalize rows, scale by sqrt(2log2e) -> bf16 Z; fp32 pos dots ----
__global__ void prep_kernel(const float* __restrict__ zi,
                            const float* __restrict__ zj,
                            __hip_bfloat16* __restrict__ Zb,
                            float* __restrict__ posdot, int N) {
    int r = blockIdx.x * 4 + (threadIdx.x >> 6);   // 4 rows per 256-thread block
    int t = threadIdx.x & 63;
    const float* pi = zi + (size_t)r * D_DIM;
    const float* pj = zj + (size_t)r * D_DIM;
    float a0 = pi[t], a1 = pi[t + 64];
    float b0 = pj[t], b1 = pj[t + 64];
    float ssi = a0*a0 + a1*a1;
    float ssj = b0*b0 + b1*b1;
    float sij = a0*b0 + a1*b1;
#pragma unroll
    for (int off = 1; off < 64; off <<= 1) {
        ssi += __shfl_xor(ssi, off);
        ssj += __shfl_xor(ssj, off);
        sij += __shfl_xor(sij, off);
    }
    float ni = sqrtf(ssi), nj = sqrtf(ssj);
    float ri = SCALE_F / ni, rj = SCALE_F / nj;
    __hip_bfloat16* zr0 = Zb + (size_t)r * D_DIM;
    __hip_bfloat16* zr1 = Zb + (size_t)(r + N) * D_DIM;
    zr0[t]      = __float2bfloat16(a0 * ri);
    zr0[t + 64] = __float2bfloat16(a1 * ri);
    zr1[t]      = __float2bfloat16(b0 * rj);
    zr1[t + 64] = __float2bfloat16(b1 * rj);
    if (t == 0) posdot[r] = sij / fmaxf(ni * nj, 1e-8f);
}

// ---- main: symmetric fused Gram x exp2, row-sums + col-sums ----
// grid (32 pairs, CS); 512 threads = 8 waves: 4 M-waves (32 rows) x 2 N-halves.
// Block (p,q): row-blocks rx=p and rx'=63-p (128 rows each); upper-triangle
// col-tiles k0, k0+16, ... of each. Each exp'd element feeds the row-sum AND
// (via kg-shuffle reduce) the col-sum plane colpart[rx*4+mw][col].
__global__ __launch_bounds__(512, 4)
void main_kernel(const ushort* __restrict__ Zu,
                 float* __restrict__ rowpart,
                 float* __restrict__ colpart, int N2) {
    __shared__ ushort Btile[2][CTILE * D_DIM];   // 2 x 16 KB

    const int tid  = threadIdx.x;
    const int lane = tid & 63;
    const int wave = tid >> 6;      // 0..7
    const int mw   = wave & 3;      // M-wave: which 32-row group
    const int nh   = wave >> 2;     // N-half: which 32 cols of the tile
    const int m    = lane & 15;
    const int kg   = lane >> 4;
    const int q    = blockIdx.y;
    const int pair = blockIdx.x;
    const int rxA  = pair;          // 0..31
    const int rxB  = 63 - pair;     // 63..32
    const int K1   = 128 - 2 * rxA;

    // staging coords (shared by both phases): LDS dest LINEAR, source pre-swizzled
    const int srow0 = tid >> 4,        sslot0 = (tid & 15) ^ (srow0 & 7);
    const int srow1 = 32 + (tid >> 4), sslot1 = (tid & 15) ^ (srow1 & 7);
    const size_t tadv = (size_t)CS * CTILE * D_DIM;   // cols advance 1024/tile-step

    for (int ph = 0; ph < 2; ++ph) {
        const int rx0 = ph ? rxB : rxA;
        const int K   = ph ? (128 - 2 * rxB) : K1;
        const int k0  = ph ? ((q - K1) & 15) : q;
        const int nt  = (K > k0) ? ((K - k0 + 15) >> 4) : 0;
        const int rwave0 = rx0 * 128 + mw * 32;

        // A fragments: 2 row-blocks x 4 k-steps = 32 VGPRs, pinned resident.
        short8 afrag[MREP][4];
#pragma unroll
        for (int rb = 0; rb < MREP; ++rb) {
            const ushort* ap = Zu + (size_t)(rwave0 + rb * 16 + m) * D_DIM + kg * 8;
#pragma unroll
            for (int ks = 0; ks < 4; ++ks)
                afrag[rb][ks] = *(const short8*)(ap + ks * 32);
        }
#pragma unroll
        for (int rb = 0; rb < MREP; ++rb)
#pragma unroll
            for (int ks = 0; ks < 4; ++ks)
                asm volatile("" : "+v"(afrag[rb][ks]));

        float rowacc[MREP][4];
#pragma unroll
        for (int rb = 0; rb < MREP; ++rb)
#pragma unroll
            for (int g = 0; g < 4; ++g) rowacc[rb][g] = 0.0f;

        if (nt > 0) {
            const int c0base = rx0 * 128 + k0 * 64;
            const ushort* gsrc0 = Zu + (size_t)(c0base + srow0) * D_DIM + sslot0 * 8;
            const ushort* gsrc1 = Zu + (size_t)(c0base + srow1) * D_DIM + sslot1 * 8;

            GLOAD16(gsrc0, &Btile[0][(size_t)tid * 8]);
            GLOAD16(gsrc1, &Btile[0][(size_t)(512 + tid) * 8]);
            __syncthreads();

            for (int t = 0; t < nt; ++t) {
                if (t + 1 < nt) {
                    ushort* nbuf = Btile[(t + 1) & 1];
                    GLOAD16(gsrc0 + (size_t)(t + 1) * tadv, &nbuf[(size_t)tid * 8]);
                    GLOAD16(gsrc1 + (size_t)(t + 1) * tadv, &nbuf[(size_t)(512 + tid) * 8]);
                }

                const ushort* buf = Btile[t & 1];
                const int c0 = c0base + t * (CS * CTILE);
                const bool dt = (t == 0) && (k0 < 2);   // diagonal 128-square tile

#pragma unroll
                for (int s2 = 0; s2 < 2; ++s2) {
                    const int brow = nh * 32 + s2 * 16 + m;
                    short8 bfrag[4];
#pragma unroll
                    for (int ks = 0; ks < 4; ++ks) {
                        int ss = (ks * 4 + kg) ^ (brow & 7);
                        bfrag[ks] = *(const short8*)&buf[brow * D_DIM + ss * 8];
                    }
                    const int gc = c0 + brow;   // this lane's global column
                    float cf = 0.0f;
#pragma unroll
                    for (int rb = 0; rb < MREP; ++rb) {
                        floatx4 ac0 = {0.f, 0.f, 0.f, 0.f};
                        floatx4 ac1 = {0.f, 0.f, 0.f, 0.f};
                        ac0 = __builtin_amdgcn_mfma_f32_16x16x32_bf16(afrag[rb][0], bfrag[0], ac0, 0, 0, 0);
                        ac1 = __builtin_amdgcn_mfma_f32_16x16x32_bf16(afrag[rb][2], bfrag[2], ac1, 0, 0, 0);
                        ac0 = __builtin_amdgcn_mfma_f32_16x16x32_bf16(afrag[rb][1], bfrag[1], ac0, 0, 0, 0);
                        ac1 = __builtin_amdgcn_mfma_f32_16x16x32_bf16(afrag[rb][3], bfrag[3], ac1, 0, 0, 0);
#pragma unroll
                        for (int g = 0; g < 4; ++g) {
                            float arg = ac0[g] + ac1[g];
                            if (dt) {
                                int gr = rwave0 + rb * 16 + kg * 4 + g;
                                arg = (gc > gr) ? arg : -1000.0f;   // strict upper triangle
                            }
                            float e = __builtin_amdgcn_exp2f(arg);
                            rowacc[rb][g] += e;
                            cf += e;
                        }
                    }
                    // col-sum over this wave's 32 rows: reduce across kg groups
                    cf += __shfl_xor(cf, 16);
                    cf += __shfl_xor(cf, 32);
                    if (lane < 16)
                        colpart[(size_t)(rx0 * 4 + mw) * N2 + gc] = cf;
                }
                __syncthreads();
            }
        }

        // row partials: reduce across the 16 column lanes, write plane (q*2+nh)
#pragma unroll
        for (int rb = 0; rb < MREP; ++rb)
#pragma unroll
            for (int g = 0; g < 4; ++g) {
                float v = rowacc[rb][g];
                v += __shfl_xor(v, 1);
                v += __shfl_xor(v, 2);
                v += __shfl_xor(v, 4);
                v += __shfl_xor(v, 8);
                if (m == 0) {
                    int grow = rwave0 + rb * 16 + kg * 4 + g;
                    rowpart[(size_t)(q * 2 + nh) * N2 + grow] = v;
                }
            }
        if (ph == 0) __syncthreads();   // Btile safe before phase-2 prologue
    }
}

// ---- finalize stage 1: per-row loss; block b owns rows [b*128, b*128+128) ----
// All rows in a block share r>>7 == b, so the colpart plane bound (b+1)*4 is
// wave-uniform -> unrollable, pipelined loads (the R10 version was a divergent
// runtime-bound serial loop at 0.5 waves/CU: 61 us of pure load latency).
__global__ void finalize1_kernel(const float* __restrict__ rowpart,
                                 const float* __restrict__ colpart,
                                 const float* __restrict__ posdot,
                                 float* __restrict__ bpart, int N2, int NP) {
    __shared__ float red[2];
    const int tid = threadIdx.x;                 // 0..127
    const int b   = blockIdx.x;                  // 0..63
    const int r   = b * 128 + tid;
    float d0 = 0.f, d1 = 0.f, d2 = 0.f, d3 = 0.f;
#pragma unroll
    for (int p = 0; p < 2 * CS; p += 4) {
        d0 += rowpart[(size_t)(p + 0) * N2 + r];
        d1 += rowpart[(size_t)(p + 1) * N2 + r];
        d2 += rowpart[(size_t)(p + 2) * N2 + r];
        d3 += rowpart[(size_t)(p + 3) * N2 + r];
    }
    const int nplanes = (b + 1) * 4;             // uniform scalar bound
#pragma unroll 4
    for (int pl = 0; pl < nplanes; pl += 4) {
        d0 += colpart[(size_t)(pl + 0) * N2 + r];
        d1 += colpart[(size_t)(pl + 1) * N2 + r];
        d2 += colpart[(size_t)(pl + 2) * N2 + r];
        d3 += colpart[(size_t)(pl + 3) * N2 + r];
    }
    float denom = (d0 + d1) + (d2 + d3);
    float pos = posdot[r < NP ? r : r - NP];
    float v = logf(denom) - 2.0f * pos;          // -log(num/denom), 1/t = 2
#pragma unroll
    for (int off = 1; off < 64; off <<= 1) v += __shfl_xor(v, off);
    if ((tid & 63) == 0) red[tid >> 6] = v;
    __syncthreads();
    if (tid == 0) bpart[b] = red[0] + red[1];
}

// ---- finalize stage 2: mean over 64 block partials ----
__global__ void finalize2_kernel(const float* __restrict__ bpart,
                                 float* __restrict__ out, int nb, int N2) {
    int t = threadIdx.x;  // 64
    float v = (t < nb) ? bpart[t] : 0.0f;
#pragma unroll
    for (int off = 1; off < 64; off <<= 1) v += __shfl_xor(v, off);
    if (t == 0) out[0] = v / (float)N2;
}

extern "C" void kernel_launch(void* const* d_in, const int* in_sizes, int n_in,
                              void* d_out, int out_size, void* d_ws, size_t ws_size,
                              hipStream_t stream) {
    const float* zi = (const float*)d_in[0];
    const float* zj = (const float*)d_in[1];
    const int N  = in_sizes[0] / D_DIM;   // 4096
    const int N2 = 2 * N;                 // 8192

    char* w = (char*)d_ws;
    __hip_bfloat16* Zb = (__hip_bfloat16*)w;
    size_t off = (size_t)N2 * D_DIM * sizeof(__hip_bfloat16);        // 2 MB
    float* posdot  = (float*)(w + off);  off += (size_t)N  * sizeof(float);
    float* rowpart = (float*)(w + off);  off += (size_t)(2 * CS) * N2 * sizeof(float);   // 1 MB
    float* colpart = (float*)(w + off);  off += (size_t)(NRXB * 4) * N2 * sizeof(float); // 8 MB
    float* bpart   = (float*)(w + off);

    prep_kernel<<<N / 4, 256, 0, stream>>>(zi, zj, Zb, posdot, N);
    dim3 grid(32, CS);
    main_kernel<<<grid, 512, 0, stream>>>((const ushort*)Zb, rowpart, colpart, N2);
    finalize1_kernel<<<NRXB, 128, 0, stream>>>(rowpart, colpart, posdot, bpart, N2, N);
    finalize2_kernel<<<1, 64, 0, stream>>>(bpart, (float*)d_out, NRXB, N2);
}